// Round 3
// baseline (5198.320 us; speedup 1.0000x reference)
//
#include <hip/hip_runtime.h>
#include <math.h>

#define BB 256
#define SS 512
#define II 128
#define HH 256

typedef unsigned short ushort_t;
typedef unsigned int uint32;

// d_ws bf16 blob element offsets (each a multiple of 8 -> 16B aligned)
#define OFF_WA   0          // 128*384 = 49152   (swizzled, 48 chunks)
#define OFF_BA   49152      // 128
#define OFF_WIH  49280      // 768*128 = 98304   (swizzled, 16 chunks)
#define OFF_BIH  147584     // 768
#define OFF_WHH  148352     // 768*256 = 196608  (swizzled, 32 chunks)
#define OFF_BHH  344960     // 768
#define OFF_WT   345728     // 256
#define OFF_BT   345984     // 1 (padded to 8)
#define OFF_WF   345992     // 256
#define OFF_BF   346248     // 1 (padded to 8)
#define OFF_WAH  346256     // 128*256 = 32768   (Wa h-part only, swizzled, 32 chunks)
#define OFF_GIX  379024     // fp32 [B,S,128] precomputed Wa_x . x_t  (element off in ushort units)

// Whh residency: 8 chunks in LDS (96 KB); 24 chunks streamed through a
// 4-slot-per-wave LDS DMA ring (48 KB) via global_load_lds (zero VGPR cost).
#define WHH_LC   8
#define NSLOT    4
#define NSTREAM  (32 - WHH_LC)          // 24
#define WRAP_IT  (NSTREAM - NSLOT - 1)  // 19: after this refill, wrap to chunk 8

__device__ __forceinline__ float b2f(ushort_t u) {
    union { uint32 i; float f; } v; v.i = ((uint32)u) << 16; return v.f;
}
__device__ __forceinline__ float lo2f(uint32 w) {
    union { uint32 i; float f; } v; v.i = w << 16; return v.f;
}
__device__ __forceinline__ float hi2f(uint32 w) {
    union { uint32 i; float f; } v; v.i = w & 0xFFFF0000u; return v.f;
}
__device__ __forceinline__ ushort_t f2b(float f) {
    union { float f; uint32 i; } v; v.f = f;
    uint32 r = (v.i + 0x7FFFu + ((v.i >> 16) & 1u)) >> 16;
    return (ushort_t)r;
}
__device__ __forceinline__ uint32 pack2(float a, float b) {
    return (uint32)f2b(a) | ((uint32)f2b(b) << 16);
}

// packed-bf16 dual-MAC: v_dot2_f32_bf16 if available, unpack+fma fallback
#if __has_builtin(__builtin_amdgcn_fdot2_f32_bf16)
typedef __bf16 v2bf __attribute__((ext_vector_type(2)));
__device__ __forceinline__ float dot2u(uint32 w, uint32 v, float acc) {
    return __builtin_amdgcn_fdot2_f32_bf16(
        __builtin_bit_cast(v2bf, w), __builtin_bit_cast(v2bf, v), acc, false);
}
#else
__device__ __forceinline__ float dot2u(uint32 w, uint32 v, float acc) {
    acc = fmaf(lo2f(w), lo2f(v), acc);
    return fmaf(hi2f(w), hi2f(v), acc);
}
#endif
__device__ __forceinline__ float dot4(uint4 w, uint4 v, float acc) {
    acc = dot2u(w.x, v.x, acc); acc = dot2u(w.y, v.y, acc);
    acc = dot2u(w.z, v.z, acc); return dot2u(w.w, v.w, acc);
}

// async global -> LDS, 16B per lane (lands at lds_base + lane*16)
__device__ __forceinline__ void lds_dma16(const uint4* g, uint4* l) {
    __builtin_amdgcn_global_load_lds(
        (const __attribute__((address_space(1))) void*)g,
        (__attribute__((address_space(3))) void*)l, 16, 0, 0);
}

// workgroup barrier WITHOUT vmcnt drain: LDS ops ordered, DMA stays in flight
__device__ __forceinline__ void barrier_soft() {
    asm volatile("s_waitcnt lgkmcnt(0)" ::: "memory");
    __builtin_amdgcn_s_barrier();
    asm volatile("" ::: "memory");
}

__global__ void cvt_f32_bf16(const float* __restrict__ src, ushort_t* __restrict__ dst, int n) {
    int i = blockIdx.x * 256 + threadIdx.x;
    if (i < n) dst[i] = f2b(src[i]);
}

// Swizzled fp32 -> bf16 with explicit source row stride / column offset:
// uint4 index = ((row/64)*chunks + c)*64 + (row%64)
__global__ void cvt_swz(const float* __restrict__ src, ushort_t* __restrict__ dst,
                        int rows, int chunks, int srcStride, int colOff) {
    int t = blockIdx.x * 256 + threadIdx.x;
    if (t >= rows * chunks) return;
    int row = t / chunks, c = t % chunks;
    const float* s = src + (size_t)row * srcStride + colOff + c * 8;
    uint4 v;
    v.x = pack2(s[0], s[1]); v.y = pack2(s[2], s[3]);
    v.z = pack2(s[4], s[5]); v.w = pack2(s[6], s[7]);
    ((uint4*)dst)[((size_t)(row >> 6) * chunks + c) * 64 + (row & 63)] = v;
}

// Pre-pass: gix[b,t,i] = dot(Wa_x[i,:], x[b,t,:])  (x-part of attention scores,
// h-independent -> hoisted out of the serial recurrence). fp32 output.
__global__ __launch_bounds__(512, 2) void gix_kernel(
    const float* __restrict__ x, const ushort_t* __restrict__ wsb,
    float* __restrict__ gix)
{
    const int b = blockIdx.x, tid = threadIdx.x;
    const int r4 = tid >> 7, i = tid & 127;
    __shared__ __align__(16) uint32 sxp[4][64];      // 4 rows of packed bf16 x

    uint4 w[16];
    const uint4* wa_g = (const uint4*)(wsb + OFF_WA);
    const size_t gb = (size_t)(i >> 6) * 48 * 64 + (i & 63);
    #pragma unroll
    for (int c = 0; c < 16; ++c) w[c] = wa_g[gb + (size_t)c * 64];

    const float* xb = x + (size_t)b * SS * II;
    float* gout = gix + (size_t)b * SS * II;
    for (int j = 0; j < SS; j += 4) {
        float v = xb[(j + r4) * II + i];
        float vn = __shfl_down(v, 1);
        if (!(i & 1)) sxp[r4][i >> 1] = pack2(v, vn);
        __syncthreads();
        const uint4* sx4 = (const uint4*)sxp[r4];
        float acc = 0.f;
        #pragma unroll
        for (int c = 0; c < 16; ++c) acc = dot4(w[c], sx4[c], acc);
        gout[(j + r4) * II + i] = acc;
        __syncthreads();
    }
}

// One block (1024 threads) per batch row.
// Waves 0-11 ("gate"): thread tid owns row tid of Wih (reg-resident, AGPRs) +
//   Whh: 8 chunks LDS-resident, 24 streamed via a per-wave 4-slot LDS DMA ring
//   (global_load_lds, vmcnt(3) discipline, never drained; ring wraps across
//   steps so the L2->CU stream runs continuously through B1/B2).
// Waves 12-15 ("attn"):
//   GIX=1: Wa_h fully reg-resident; x-part of scores from precomputed gix.
//   GIX=0: full Wa; 16/24 chunks in regs, 8 streamed.
// 2 soft barriers (no vmcnt drain) + 2 LDS flag syncs per step.
template <int GIX>
__global__ __launch_bounds__(1024, 4) void da_rnn_kernel(
    const float* __restrict__ x,          // fp32 [B,S,I]
    const ushort_t* __restrict__ wsb,     // bf16 blob in d_ws
    const float* __restrict__ gix,        // fp32 [B,S,I] precomputed (GIX=1 only)
    float* __restrict__ out)              // fp32 [B,1]
{
    const int b    = blockIdx.x;
    const int tid  = threadIdx.x;
    const int lane = tid & 63;
    const int wv   = tid >> 6;
    const bool is_gate = (tid < 3 * HH);

    __shared__ __align__(16) uint32 whh_lds[WHH_LC * 768 * 4];   // 96 KB resident
    __shared__ __align__(16) uint32 ring_lds[12 * NSLOT * 256];  // 48 KB DMA ring
    __shared__ __align__(16) uint32 s_xh_p[192];     // packed bf16 [x_t(128); h(256)]
    __shared__ __align__(16) uint32 sxw_p[64];       // packed bf16 alpha*x_t
    __shared__ __align__(16) float  sred[256];
    __shared__ __align__(16) float  sgi[3 * HH];     // input-side gate pre-acts
    __shared__ __align__(16) float  sgh[3 * HH];     // hidden-side gate pre-acts
    __shared__ __align__(16) float  sx[2][II];       // x_t fp32 double buffer
    __shared__ __align__(16) float  sgix[2][II];     // gix_t fp32 double buffer
    __shared__ float swave[4];
    __shared__ int   flag_red;   // attn-wave arrival counter (monotonic)
    __shared__ int   flag_xw;    // sxw_p ready for step t (== t+1)

    if (tid == 0) { flag_red = 0; flag_xw = 0; }
    if (tid < II) s_xh_p[64 + tid] = 0u;             // h_0 = 0 (packed)

    // ---- role-overlaid register-resident weights (one 64-VGPR array) ----
    uint4 wreg[16];
    const int a   = tid - 3 * HH;                    // attn index 0..255
    const int row = a & 127;
    const int s   = a >> 7;
    const uint4* whh_base = (const uint4*)(wsb + OFF_WHH) + (size_t)wv * 32 * 64 + lane;
    const uint4* wa_st = nullptr;
    float bias_i = 0.f, bias_h = 0.f, ba_a = 0.f, ba_b = 0.f;

    if (is_gate) {
        const uint4* wih_g = (const uint4*)(wsb + OFF_WIH) + (size_t)wv * 16 * 64 + lane;
        #pragma unroll
        for (int c = 0; c < 16; ++c) wreg[c] = wih_g[c * 64];
        bias_i = b2f(wsb[OFF_BIH + tid]);
        bias_h = b2f(wsb[OFF_BHH + tid]);
        #pragma unroll
        for (int c = 0; c < WHH_LC; ++c)
            ((uint4*)whh_lds)[(wv * WHH_LC + c) * 64 + lane] = whh_base[c * 64];
    } else {
        if (GIX) {
            const uint4* wah_g = (const uint4*)(wsb + OFF_WAH);
            const size_t gbh = ((size_t)(row >> 6) * 32 + s * 16) * 64 + (row & 63);
            #pragma unroll
            for (int i = 0; i < 16; ++i) wreg[i] = wah_g[gbh + (size_t)i * 64];
        } else {
            const uint4* wa_g = (const uint4*)(wsb + OFF_WA);
            const size_t gbase = ((size_t)(row >> 6) * 48 + s * 24) * 64 + (row & 63);
            #pragma unroll
            for (int i = 0; i < 16; ++i) wreg[i] = wa_g[gbase + (size_t)i * 64];
            wa_st = wa_g + gbase + (size_t)16 * 64;  // streamed chunks 16..23
        }
        ba_a = b2f(wsb[OFF_BA + lane]);
        ba_b = b2f(wsb[OFF_BA + 64 + lane]);
    }

    float h_reg = 0.f, c_reg = 0.f, m_run = -2.0f, l_run = 0.f;
    float wt_j = 0.f, wf_j = 0.f, bt_r = 0.f;
    if (tid < HH) {
        wt_j = b2f(wsb[OFF_WT + tid]);
        wf_j = b2f(wsb[OFF_WF + tid]);
        bt_r = b2f(wsb[OFF_BT]);
    }

    const float* xrow  = x + (size_t)b * SS * II;
    const float* grow0 = GIX ? (gix + (size_t)b * SS * II) : nullptr;
    if (!is_gate && a >= 64 && a < 192) {            // x_0 load (+ pack if !GIX)
        const int idx = a - 64;
        float v = xrow[idx];
        sx[0][idx] = v;
        if (!GIX) {
            float vn = __shfl_down(v, 1);
            if (!(idx & 1)) s_xh_p[idx >> 1] = pack2(v, vn);
        }
    }
    if (GIX && !is_gate && a >= 192) {               // gix_0 load
        const int l = a - 192;
        sgix[0][l]      = grow0[l];
        sgix[0][64 + l] = grow0[64 + l];
    }
    __syncthreads();   // full barrier: resident Whh copy + h0/x0 visible

    uint4* const ring4 = (uint4*)ring_lds;
    const int ring_idx = wv * NSLOT * 64;            // wave-uniform slot base
    const uint4* nxt = whh_base + (WHH_LC + NSLOT) * 64;

    // prime the ring: chunks 8..11 in flight (vmcnt = 4 outstanding)
    if (is_gate) {
        #pragma unroll
        for (int s2 = 0; s2 < NSLOT; ++s2)
            lds_dma16(whh_base + (WHH_LC + s2) * 64, ring4 + ring_idx + s2 * 64);
    }

    const uint4* st4 = (const uint4*)s_xh_p;         // 48 chunks of [x;h]
    const uint4* shp = (const uint4*)s_xh_p + 16;    // 32 chunks of h
    const uint4* xwp = (const uint4*)sxw_p;          // 16 chunks of xw
    const uint4* whl = (const uint4*)whh_lds + (size_t)(wv * WHH_LC) * 64 + lane;

    for (int t = 0; t < SS; ++t) {
        const int p = t & 1;

        if (is_gate) {
            // gh = Whh . h_t : 8 LDS-resident chunks, then 24 ring-streamed.
            float g0 = bias_h, g1 = 0.f, g2 = 0.f, g3 = 0.f;
            #pragma unroll
            for (int c = 0; c < WHH_LC; c += 4) {
                g0 = dot4(whl[(c + 0) * 64], shp[c + 0], g0);
                g1 = dot4(whl[(c + 1) * 64], shp[c + 1], g1);
                g2 = dot4(whl[(c + 2) * 64], shp[c + 2], g2);
                g3 = dot4(whl[(c + 3) * 64], shp[c + 3], g3);
            }
            #pragma unroll
            for (int i = 0; i < NSTREAM; ++i) {
                const int sl = i & 3;
                // oldest DMA (this chunk) landed; 3 stay in flight
                asm volatile("s_waitcnt vmcnt(3)" ::: "memory");
                uint4 w = ring4[ring_idx + sl * 64 + lane];     // ds_read_b128
                // slot read complete -> safe to refill it (lgkm is in-order)
                asm volatile("s_waitcnt lgkmcnt(0)" ::: "memory");
                __builtin_amdgcn_sched_barrier(0);
                lds_dma16(nxt, ring4 + ring_idx + sl * 64);
                nxt += 64;
                if (i == WRAP_IT) nxt = whh_base + WHH_LC * 64; // wrap: prime t+1
                if      (sl == 0) g0 = dot4(w, shp[WHH_LC + i], g0);
                else if (sl == 1) g1 = dot4(w, shp[WHH_LC + i], g1);
                else if (sl == 2) g2 = dot4(w, shp[WHH_LC + i], g2);
                else              g3 = dot4(w, shp[WHH_LC + i], g3);
            }
            sgh[tid] = (g0 + g1) + (g2 + g3);
            // wait for xw, then reg-resident Wih dot
            while (__hip_atomic_load(&flag_xw, __ATOMIC_ACQUIRE,
                                     __HIP_MEMORY_SCOPE_WORKGROUP) <= t) {}
            float gi = bias_i;
            #pragma unroll
            for (int c = 0; c < 16; ++c) gi = dot4(wreg[c], xwp[c], gi);
            sgi[tid] = gi;
        } else {
            // Wa partials: GIX -> 16 reg chunks (h only); else 16 reg + 8 streamed
            float acc;
            if (GIX) {
                float a0 = 0.f, a1 = 0.f;
                #pragma unroll
                for (int i = 0; i < 16; i += 2) {
                    a0 = dot4(wreg[i + 0], shp[s * 16 + i + 0], a0);
                    a1 = dot4(wreg[i + 1], shp[s * 16 + i + 1], a1);
                }
                acc = a0 + a1;
            } else {
                acc = 0.f;
                #pragma unroll
                for (int i = 0; i < 16; ++i) acc = dot4(wreg[i], st4[s * 24 + i], acc);
                #pragma unroll 4
                for (int i = 0; i < 8; ++i) acc = dot4(wa_st[i * 64], st4[s * 24 + 16 + i], acc);
            }
            sred[a] = acc;
            if (lane == 0)
                __hip_atomic_fetch_add(&flag_red, 1, __ATOMIC_ACQ_REL,
                                       __HIP_MEMORY_SCOPE_WORKGROUP);
            const int tgt = 4 * (t + 1);
            while (__hip_atomic_load(&flag_red, __ATOMIC_ACQUIRE,
                                     __HIP_MEMORY_SCOPE_WORKGROUP) < tgt) {}
            if (a < 64) {
                // wave 12: combine + tanh + softmax + packed xw
                float s_a = sred[lane] + sred[128 + lane] + ba_a;
                float s_b = sred[64 + lane] + sred[192 + lane] + ba_b;
                if (GIX) { s_a += sgix[p][lane]; s_b += sgix[p][64 + lane]; }
                s_a = tanhf(s_a); s_b = tanhf(s_b);
                float m = fmaxf(s_a, s_b);
                for (int off = 32; off; off >>= 1) m = fmaxf(m, __shfl_xor(m, off));
                float e_a = expf(s_a - m), e_b = expf(s_b - m);
                float sum = e_a + e_b;
                for (int off = 32; off; off >>= 1) sum += __shfl_xor(sum, off);
                float inv = 1.f / sum;
                float xa = e_a * inv * sx[p][lane];
                float xb = e_b * inv * sx[p][64 + lane];
                float xa1 = __shfl_down(xa, 1), xb1 = __shfl_down(xb, 1);
                if (!(lane & 1)) {
                    sxw_p[lane >> 1]        = pack2(xa, xa1);
                    sxw_p[32 + (lane >> 1)] = pack2(xb, xb1);
                }
                if (lane == 0)
                    __hip_atomic_store(&flag_xw, t + 1, __ATOMIC_RELEASE,
                                       __HIP_MEMORY_SCOPE_WORKGROUP);
            } else if (a >= 64 && a < 192 && t + 1 < SS) {
                // waves 13-14: prefetch x_{t+1}
                const int idx = a - 64;
                float v = xrow[(t + 1) * II + idx];
                sx[p ^ 1][idx] = v;
                if (!GIX) {
                    float vn = __shfl_down(v, 1);
                    if (!(idx & 1)) s_xh_p[idx >> 1] = pack2(v, vn);
                }
            } else if (GIX && a >= 192 && t + 1 < SS) {
                // wave 15: prefetch gix_{t+1}
                const float* gr = grow0 + (size_t)(t + 1) * II;
                const int l = a - 192;
                sgix[p ^ 1][l]      = gr[l];
                sgix[p ^ 1][64 + l] = gr[64 + l];
            }
        }
        barrier_soft();                               // B1: gates done (DMAs live)

        if (tid < HH) {
            const float r = 1.f / (1.f + expf(-(sgi[tid] + sgh[tid])));
            const float z = 1.f / (1.f + expf(-(sgi[tid + HH] + sgh[tid + HH])));
            const float n = tanhf(sgi[tid + 2 * HH] + r * sgh[tid + 2 * HH]);
            h_reg = (1.f - z) * n + z * h_reg;
            float hn2 = __shfl_down(h_reg, 1);
            if (!(tid & 1)) s_xh_p[64 + (tid >> 1)] = pack2(h_reg, hn2);
            float pd = wt_j * h_reg;
            for (int off = 32; off; off >>= 1) pd += __shfl_down(pd, off);
            if (lane == 0) swave[wv] = pd;
        }
        barrier_soft();                               // B2: h ready (DMAs live)

        if (tid < HH) {
            // redundant per-thread online softmax over time (no extra barrier)
            float dot = swave[0] + swave[1] + swave[2] + swave[3] + bt_r;
            float st = tanhf(dot);
            float mn = fmaxf(m_run, st);
            float aa = expf(m_run - mn), ww = expf(st - mn);
            l_run = l_run * aa + ww;
            m_run = mn;
            c_reg = c_reg * aa + ww * h_reg;
        }
    }

    __syncthreads();   // full barrier (drains any remaining ring DMAs)
    if (tid < HH) {
        float ctx = c_reg / l_run;
        float pd = wf_j * ctx;
        for (int off = 32; off; off >>= 1) pd += __shfl_down(pd, off);
        if (lane == 0) swave[wv] = pd;
    }
    __syncthreads();
    if (tid == 0) {
        float logit = swave[0] + swave[1] + swave[2] + swave[3] + b2f(wsb[OFF_BF]);
        out[b] = 1.f / (1.f + expf(-logit));
    }
}

extern "C" void kernel_launch(void* const* d_in, const int* in_sizes, int n_in,
                              void* d_out, int out_size, void* d_ws, size_t ws_size,
                              hipStream_t stream) {
    ushort_t* wsb = (ushort_t*)d_ws;
    const size_t WS_NEED = (size_t)OFF_GIX * 2 + (size_t)BB * SS * II * 4;
    const bool use_gix = ws_size >= WS_NEED;

    cvt_swz<<<dim3((128 * 48 + 255) / 256), dim3(256), 0, stream>>>(
        (const float*)d_in[1], wsb + OFF_WA, 128, 48, 384, 0);       // W_a  [128,384]
    cvt_swz<<<dim3((768 * 16 + 255) / 256), dim3(256), 0, stream>>>(
        (const float*)d_in[3], wsb + OFF_WIH, 768, 16, 128, 0);      // W_ih [768,128]
    cvt_swz<<<dim3((768 * 32 + 255) / 256), dim3(256), 0, stream>>>(
        (const float*)d_in[5], wsb + OFF_WHH, 768, 32, 256, 0);      // W_hh [768,256]
    if (use_gix)
        cvt_swz<<<dim3((128 * 32 + 255) / 256), dim3(256), 0, stream>>>(
            (const float*)d_in[1], wsb + OFF_WAH, 128, 32, 384, 128); // W_a h-part

    struct { int src_idx; int off; int n; } cv[7] = {
        {2, OFF_BA,  II}, {4, OFF_BIH, 3 * HH}, {6, OFF_BHH, 3 * HH},
        {7, OFF_WT,  HH}, {8, OFF_BT, 1}, {9, OFF_WF, HH}, {10, OFF_BF, 1},
    };
    for (int i = 0; i < 7; ++i) {
        int blocks = (cv[i].n + 255) / 256;
        cvt_f32_bf16<<<dim3(blocks), dim3(256), 0, stream>>>(
            (const float*)d_in[cv[i].src_idx], wsb + cv[i].off, cv[i].n);
    }

    float* gixf = (float*)(wsb + OFF_GIX);
    if (use_gix) {
        gix_kernel<<<dim3(BB), dim3(512), 0, stream>>>(
            (const float*)d_in[0], wsb, gixf);
        da_rnn_kernel<1><<<dim3(BB), dim3(1024), 0, stream>>>(
            (const float*)d_in[0], wsb, gixf, (float*)d_out);
    } else {
        da_rnn_kernel<0><<<dim3(BB), dim3(1024), 0, stream>>>(
            (const float*)d_in[0], wsb, nullptr, (float*)d_out);
    }
}

// Round 4
// 2393.790 us; speedup vs baseline: 2.1716x; 2.1716x over previous
//
#include <hip/hip_runtime.h>
#include <math.h>

#define BB 256
#define SS 512
#define II 128
#define HH 256

typedef unsigned short ushort_t;
typedef unsigned int uint32;

// d_ws f16 blob element offsets (each a multiple of 8 -> 16B aligned)
#define OFF_WA   0          // 128*384 = 49152   (swizzled, 48 chunks)
#define OFF_BA   49152      // 128
#define OFF_WIH  49280      // 768*128 = 98304   (swizzled, 16 chunks)
#define OFF_BIH  147584     // 768
#define OFF_WHH  148352     // 768*256 = 196608  (swizzled, 32 chunks)
#define OFF_BHH  344960     // 768
#define OFF_WT   345728     // 256
#define OFF_BT   345984     // 1 (padded to 8)
#define OFF_WF   345992     // 256
#define OFF_BF   346248     // 1 (padded to 8)
#define OFF_WAH  346256     // 128*256 = 32768   (Wa h-part only, swizzled, 32 chunks)
#define OFF_GIX  379024     // fp32 [B,S,128] precomputed Wa_x . x_t  (element off in ushort units)

// number of Whh chunks resident in LDS (of 32). 12 chunks = 144 KB.
#define WHH_LC   12

// ---------- f16 helpers (f16 chosen over bf16: v_dot2_f32_f16 exists on
// gfx950, bf16 dot does not -> bf16 path was a 4-instr unpack+fma fallback.
// All operands here are bounded (|W|<=1/16, |h|<=1, x~N(0,1)) so f16 range
// is safe and its 10 mantissa bits beat bf16's 7.)
__device__ __forceinline__ float h2f(ushort_t u) {
    union { ushort_t s[2]; _Float16 h[2]; } v; v.s[0] = u; return (float)v.h[0];
}
__device__ __forceinline__ ushort_t f2h(float f) {
    union { _Float16 h; ushort_t s; } v; v.h = (_Float16)f; return v.s;
}
__device__ __forceinline__ uint32 pack2(float a, float b) {
    union { _Float16 h[2]; uint32 u; } v;
    v.h[0] = (_Float16)a; v.h[1] = (_Float16)b; return v.u;
}

// packed-f16 dual-MAC: v_dot2_f32_f16 if available, unpack+fma fallback
#if __has_builtin(__builtin_amdgcn_fdot2)
typedef _Float16 v2h __attribute__((ext_vector_type(2)));
__device__ __forceinline__ float dot2u(uint32 w, uint32 v, float acc) {
    return __builtin_amdgcn_fdot2(
        __builtin_bit_cast(v2h, w), __builtin_bit_cast(v2h, v), acc, false);
}
#else
__device__ __forceinline__ float dot2u(uint32 w, uint32 v, float acc) {
    union { uint32 u; _Float16 h[2]; } a, b; a.u = w; b.u = v;
    acc = fmaf((float)a.h[0], (float)b.h[0], acc);
    return fmaf((float)a.h[1], (float)b.h[1], acc);
}
#endif
__device__ __forceinline__ float dot4(uint4 w, uint4 v, float acc) {
    acc = dot2u(w.x, v.x, acc); acc = dot2u(w.y, v.y, acc);
    acc = dot2u(w.z, v.z, acc); return dot2u(w.w, v.w, acc);
}

__global__ void cvt_f32_f16(const float* __restrict__ src, ushort_t* __restrict__ dst, int n) {
    int i = blockIdx.x * 256 + threadIdx.x;
    if (i < n) dst[i] = f2h(src[i]);
}

// Swizzled fp32 -> f16 with explicit source row stride / column offset:
// uint4 index = ((row/64)*chunks + c)*64 + (row%64)
__global__ void cvt_swz(const float* __restrict__ src, ushort_t* __restrict__ dst,
                        int rows, int chunks, int srcStride, int colOff) {
    int t = blockIdx.x * 256 + threadIdx.x;
    if (t >= rows * chunks) return;
    int row = t / chunks, c = t % chunks;
    const float* s = src + (size_t)row * srcStride + colOff + c * 8;
    uint4 v;
    v.x = pack2(s[0], s[1]); v.y = pack2(s[2], s[3]);
    v.z = pack2(s[4], s[5]); v.w = pack2(s[6], s[7]);
    ((uint4*)dst)[((size_t)(row >> 6) * chunks + c) * 64 + (row & 63)] = v;
}

// Pre-pass: gix[b,t,i] = dot(Wa_x[i,:], x[b,t,:])  (x-part of attention scores,
// h-independent -> hoisted out of the serial recurrence). fp32 output.
__global__ __launch_bounds__(512, 2) void gix_kernel(
    const float* __restrict__ x, const ushort_t* __restrict__ wsb,
    float* __restrict__ gix)
{
    const int b = blockIdx.x, tid = threadIdx.x;
    const int r4 = tid >> 7, i = tid & 127;
    __shared__ __align__(16) uint32 sxp[4][64];      // 4 rows of packed f16 x

    uint4 w[16];
    const uint4* wa_g = (const uint4*)(wsb + OFF_WA);
    const size_t gb = (size_t)(i >> 6) * 48 * 64 + (i & 63);
    #pragma unroll
    for (int c = 0; c < 16; ++c) w[c] = wa_g[gb + (size_t)c * 64];

    const float* xb = x + (size_t)b * SS * II;
    float* gout = gix + (size_t)b * SS * II;
    for (int j = 0; j < SS; j += 4) {
        float v = xb[(j + r4) * II + i];
        float vn = __shfl_down(v, 1);
        if (!(i & 1)) sxp[r4][i >> 1] = pack2(v, vn);
        __syncthreads();
        const uint4* sx4 = (const uint4*)sxp[r4];
        float acc = 0.f;
        #pragma unroll
        for (int c = 0; c < 16; ++c) acc = dot4(w[c], sx4[c], acc);
        gout[(j + r4) * II + i] = acc;
        __syncthreads();
    }
}

// One block (1024 threads) per batch row.  (R1 structure, f16 dots.)
// Waves 0-11 ("gate"): thread tid owns row tid of Wih (reg-resident) + Whh
//   (12 chunks LDS-resident, 20 streamed from L2).
// Waves 12-15 ("attn"):
//   GIX=1: (row 0..127) x (kslice 0..1) of Wa_h, fully reg-resident (16 chunks);
//          x-part of scores read from precomputed gix (wave 15 prefetches).
//   GIX=0: (row 0..127) x (kslice 0..1) of full Wa; 16/24 chunks in regs.
// 2 block barriers + 2 LDS flag syncs per step; Whh stream overlaps attention.
template <int GIX>
__global__ __launch_bounds__(1024, 4) void da_rnn_kernel(
    const float* __restrict__ x,          // fp32 [B,S,I]
    const ushort_t* __restrict__ wsb,     // f16 blob in d_ws
    const float* __restrict__ gix,        // fp32 [B,S,I] precomputed (GIX=1 only)
    float* __restrict__ out)              // fp32 [B,1]
{
    const int b    = blockIdx.x;
    const int tid  = threadIdx.x;
    const int lane = tid & 63;
    const int wv   = tid >> 6;
    const bool is_gate = (tid < 3 * HH);

    __shared__ __align__(16) uint32 whh_lds[WHH_LC * 768 * 4];  // 144 KB
    __shared__ __align__(16) uint32 s_xh_p[192];     // packed f16 [x_t(128); h(256)]
    __shared__ __align__(16) uint32 sxw_p[64];       // packed f16 alpha*x_t
    __shared__ __align__(16) float  sred[256];
    __shared__ __align__(16) float  sgi[3 * HH];     // input-side gate pre-acts
    __shared__ __align__(16) float  sgh[3 * HH];     // hidden-side gate pre-acts
    __shared__ __align__(16) float  sx[2][II];       // x_t fp32 double buffer
    __shared__ __align__(16) float  sgix[2][II];     // gix_t fp32 double buffer
    __shared__ float swave[4];
    __shared__ int   flag_red;   // attn-wave arrival counter (monotonic)
    __shared__ int   flag_xw;    // sxw_p ready for step t (== t+1)

    if (tid == 0) { flag_red = 0; flag_xw = 0; }
    if (tid < II) s_xh_p[64 + tid] = 0u;             // h_0 = 0 (packed)

    // ---- role-overlaid register-resident weights (one 64-VGPR array) ----
    uint4 wreg[16];
    const int a   = tid - 3 * HH;                    // attn index 0..255
    const int row = a & 127;
    const int s   = a >> 7;
    const uint4* whh_base = (const uint4*)(wsb + OFF_WHH) + (size_t)wv * 32 * 64 + lane;
    const uint4* wa_st = nullptr;
    float bias_i = 0.f, bias_h = 0.f, ba_a = 0.f, ba_b = 0.f;

    if (is_gate) {
        const uint4* wih_g = (const uint4*)(wsb + OFF_WIH) + (size_t)wv * 16 * 64 + lane;
        #pragma unroll
        for (int c = 0; c < 16; ++c) wreg[c] = wih_g[c * 64];
        bias_i = h2f(wsb[OFF_BIH + tid]);
        bias_h = h2f(wsb[OFF_BHH + tid]);
        #pragma unroll
        for (int c = 0; c < WHH_LC; ++c)
            ((uint4*)whh_lds)[(wv * WHH_LC + c) * 64 + lane] = whh_base[c * 64];
    } else {
        if (GIX) {
            const uint4* wah_g = (const uint4*)(wsb + OFF_WAH);
            const size_t gbh = ((size_t)(row >> 6) * 32 + s * 16) * 64 + (row & 63);
            #pragma unroll
            for (int i = 0; i < 16; ++i) wreg[i] = wah_g[gbh + (size_t)i * 64];
        } else {
            const uint4* wa_g = (const uint4*)(wsb + OFF_WA);
            const size_t gbase = ((size_t)(row >> 6) * 48 + s * 24) * 64 + (row & 63);
            #pragma unroll
            for (int i = 0; i < 16; ++i) wreg[i] = wa_g[gbase + (size_t)i * 64];
            wa_st = wa_g + gbase + (size_t)16 * 64;  // streamed chunks 16..23
        }
        ba_a = h2f(wsb[OFF_BA + lane]);
        ba_b = h2f(wsb[OFF_BA + 64 + lane]);
    }

    float h_reg = 0.f, c_reg = 0.f, m_run = -2.0f, l_run = 0.f;
    float wt_j = 0.f, wf_j = 0.f, bt_r = 0.f;
    if (tid < HH) {
        wt_j = h2f(wsb[OFF_WT + tid]);
        wf_j = h2f(wsb[OFF_WF + tid]);
        bt_r = h2f(wsb[OFF_BT]);
    }

    const float* xrow  = x + (size_t)b * SS * II;
    const float* grow0 = GIX ? (gix + (size_t)b * SS * II) : nullptr;
    if (!is_gate && a >= 64 && a < 192) {            // x_0 load (+ pack if !GIX)
        const int idx = a - 64;
        float v = xrow[idx];
        sx[0][idx] = v;
        if (!GIX) {
            float vn = __shfl_down(v, 1);
            if (!(idx & 1)) s_xh_p[idx >> 1] = pack2(v, vn);
        }
    }
    if (GIX && !is_gate && a >= 192) {               // gix_0 load
        const int l = a - 192;
        sgix[0][l]      = grow0[l];
        sgix[0][64 + l] = grow0[64 + l];
    }
    __syncthreads();

    const uint4* st4 = (const uint4*)s_xh_p;         // 48 chunks of [x;h]
    const uint4* shp = (const uint4*)s_xh_p + 16;    // 32 chunks of h
    const uint4* xwp = (const uint4*)sxw_p;          // 16 chunks of xw
    const uint4* whl = (const uint4*)whh_lds + (size_t)(wv * WHH_LC) * 64 + lane;

    for (int t = 0; t < SS; ++t) {
        const int p = t & 1;

        if (is_gate) {
            // gh = Whh . h_t : starts immediately, overlaps attention phase
            float gh = bias_h;
            #pragma unroll
            for (int c = 0; c < WHH_LC; ++c) gh = dot4(whl[c * 64], shp[c], gh);
            #pragma unroll 4
            for (int c = WHH_LC; c < 32; ++c) gh = dot4(whh_base[c * 64], shp[c], gh);
            sgh[tid] = gh;
            // wait for xw, then reg-resident Wih dot
            while (__hip_atomic_load(&flag_xw, __ATOMIC_ACQUIRE,
                                     __HIP_MEMORY_SCOPE_WORKGROUP) <= t) {}
            float gi = bias_i;
            #pragma unroll
            for (int c = 0; c < 16; ++c) gi = dot4(wreg[c], xwp[c], gi);
            sgi[tid] = gi;
        } else {
            // Wa partials: GIX -> 16 reg chunks (h only); else 16 reg + 8 streamed
            float acc;
            if (GIX) {
                acc = 0.f;
                #pragma unroll
                for (int i = 0; i < 16; ++i) acc = dot4(wreg[i], shp[s * 16 + i], acc);
            } else {
                acc = 0.f;
                #pragma unroll
                for (int i = 0; i < 16; ++i) acc = dot4(wreg[i], st4[s * 24 + i], acc);
                #pragma unroll 4
                for (int i = 0; i < 8; ++i) acc = dot4(wa_st[i * 64], st4[s * 24 + 16 + i], acc);
            }
            sred[a] = acc;
            if (lane == 0)
                __hip_atomic_fetch_add(&flag_red, 1, __ATOMIC_ACQ_REL,
                                       __HIP_MEMORY_SCOPE_WORKGROUP);
            const int tgt = 4 * (t + 1);
            while (__hip_atomic_load(&flag_red, __ATOMIC_ACQUIRE,
                                     __HIP_MEMORY_SCOPE_WORKGROUP) < tgt) {}
            if (a < 64) {
                // wave 12: combine + tanh + softmax + packed xw
                float s_a = sred[lane] + sred[128 + lane] + ba_a;
                float s_b = sred[64 + lane] + sred[192 + lane] + ba_b;
                if (GIX) { s_a += sgix[p][lane]; s_b += sgix[p][64 + lane]; }
                s_a = tanhf(s_a); s_b = tanhf(s_b);
                float m = fmaxf(s_a, s_b);
                for (int off = 32; off; off >>= 1) m = fmaxf(m, __shfl_xor(m, off));
                float e_a = expf(s_a - m), e_b = expf(s_b - m);
                float sum = e_a + e_b;
                for (int off = 32; off; off >>= 1) sum += __shfl_xor(sum, off);
                float inv = 1.f / sum;
                float xa = e_a * inv * sx[p][lane];
                float xb = e_b * inv * sx[p][64 + lane];
                float xa1 = __shfl_down(xa, 1), xb1 = __shfl_down(xb, 1);
                if (!(lane & 1)) {
                    sxw_p[lane >> 1]        = pack2(xa, xa1);
                    sxw_p[32 + (lane >> 1)] = pack2(xb, xb1);
                }
                if (lane == 0)
                    __hip_atomic_store(&flag_xw, t + 1, __ATOMIC_RELEASE,
                                       __HIP_MEMORY_SCOPE_WORKGROUP);
            } else if (a >= 64 && a < 192 && t + 1 < SS) {
                // waves 13-14: prefetch x_{t+1}
                const int idx = a - 64;
                float v = xrow[(t + 1) * II + idx];
                sx[p ^ 1][idx] = v;
                if (!GIX) {
                    float vn = __shfl_down(v, 1);
                    if (!(idx & 1)) s_xh_p[idx >> 1] = pack2(v, vn);
                }
            } else if (GIX && a >= 192 && t + 1 < SS) {
                // wave 15: prefetch gix_{t+1}
                const float* gr = grow0 + (size_t)(t + 1) * II;
                const int l = a - 192;
                sgix[p ^ 1][l]      = gr[l];
                sgix[p ^ 1][64 + l] = gr[64 + l];
            }
        }
        __syncthreads();                              // B1: gates done, x prefetched

        if (tid < HH) {
            const float r = 1.f / (1.f + expf(-(sgi[tid] + sgh[tid])));
            const float z = 1.f / (1.f + expf(-(sgi[tid + HH] + sgh[tid + HH])));
            const float n = tanhf(sgi[tid + 2 * HH] + r * sgh[tid + 2 * HH]);
            h_reg = (1.f - z) * n + z * h_reg;
            float hn2 = __shfl_down(h_reg, 1);
            if (!(tid & 1)) s_xh_p[64 + (tid >> 1)] = pack2(h_reg, hn2);
            float pd = wt_j * h_reg;
            for (int off = 32; off; off >>= 1) pd += __shfl_down(pd, off);
            if (lane == 0) swave[wv] = pd;
        }
        __syncthreads();                              // B2: h ready (loop barrier)

        if (tid < HH) {
            // redundant per-thread online softmax over time (no extra barrier)
            float dot = swave[0] + swave[1] + swave[2] + swave[3] + bt_r;
            float st = tanhf(dot);
            float mn = fmaxf(m_run, st);
            float aa = expf(m_run - mn), ww = expf(st - mn);
            l_run = l_run * aa + ww;
            m_run = mn;
            c_reg = c_reg * aa + ww * h_reg;
        }
    }

    __syncthreads();
    if (tid < HH) {
        float ctx = c_reg / l_run;
        float pd = wf_j * ctx;
        for (int off = 32; off; off >>= 1) pd += __shfl_down(pd, off);
        if (lane == 0) swave[wv] = pd;
    }
    __syncthreads();
    if (tid == 0) {
        float logit = swave[0] + swave[1] + swave[2] + swave[3] + h2f(wsb[OFF_BF]);
        out[b] = 1.f / (1.f + expf(-logit));
    }
}

extern "C" void kernel_launch(void* const* d_in, const int* in_sizes, int n_in,
                              void* d_out, int out_size, void* d_ws, size_t ws_size,
                              hipStream_t stream) {
    ushort_t* wsb = (ushort_t*)d_ws;
    const size_t WS_NEED = (size_t)OFF_GIX * 2 + (size_t)BB * SS * II * 4;
    const bool use_gix = ws_size >= WS_NEED;

    cvt_swz<<<dim3((128 * 48 + 255) / 256), dim3(256), 0, stream>>>(
        (const float*)d_in[1], wsb + OFF_WA, 128, 48, 384, 0);       // W_a  [128,384]
    cvt_swz<<<dim3((768 * 16 + 255) / 256), dim3(256), 0, stream>>>(
        (const float*)d_in[3], wsb + OFF_WIH, 768, 16, 128, 0);      // W_ih [768,128]
    cvt_swz<<<dim3((768 * 32 + 255) / 256), dim3(256), 0, stream>>>(
        (const float*)d_in[5], wsb + OFF_WHH, 768, 32, 256, 0);      // W_hh [768,256]
    if (use_gix)
        cvt_swz<<<dim3((128 * 32 + 255) / 256), dim3(256), 0, stream>>>(
            (const float*)d_in[1], wsb + OFF_WAH, 128, 32, 384, 128); // W_a h-part

    struct { int src_idx; int off; int n; } cv[7] = {
        {2, OFF_BA,  II}, {4, OFF_BIH, 3 * HH}, {6, OFF_BHH, 3 * HH},
        {7, OFF_WT,  HH}, {8, OFF_BT, 1}, {9, OFF_WF, HH}, {10, OFF_BF, 1},
    };
    for (int i = 0; i < 7; ++i) {
        int blocks = (cv[i].n + 255) / 256;
        cvt_f32_f16<<<dim3(blocks), dim3(256), 0, stream>>>(
            (const float*)d_in[cv[i].src_idx], wsb + cv[i].off, cv[i].n);
    }

    float* gixf = (float*)(wsb + OFF_GIX);
    if (use_gix) {
        gix_kernel<<<dim3(BB), dim3(512), 0, stream>>>(
            (const float*)d_in[0], wsb, gixf);
        da_rnn_kernel<1><<<dim3(BB), dim3(1024), 0, stream>>>(
            (const float*)d_in[0], wsb, gixf, (float*)d_out);
    } else {
        da_rnn_kernel<0><<<dim3(BB), dim3(1024), 0, stream>>>(
            (const float*)d_in[0], wsb, nullptr, (float*)d_out);
    }
}